// Round 2
// baseline (217.051 us; speedup 1.0000x reference)
//
#include <hip/hip_runtime.h>
#include <hip/hip_cooperative_groups.h>
#include <cstdint>

namespace cg = cooperative_groups;

#define INFIN __builtin_inff()

constexpr int NBLK = 256;
constexpr int NTHR = 1024;
constexpr int KMAX = 256;
constexpr int NLVL = 5;
constexpr int NWAVE = NTHR / 64;

// workspace byte offsets
constexpr size_t O_HIST  = 0;                          // NBLK*NLVL ints
constexpr size_t O_BOFF  = O_HIST + (size_t)NBLK*NLVL*4; // NBLK*NLVL ints (exclusive per-block offsets)
constexpr size_t O_MISC  = O_BOFF + (size_t)NBLK*NLVL*4; // bbase[8], bcnt[8]
constexpr size_t O_GT    = O_MISC + 256;               // 9 arrays of KMAX (cx,cy,w,h,rw,rh,lvl,org,inv)
constexpr size_t O_MIND  = O_GT + (size_t)9*KMAX*4;
constexpr size_t O_NEARG = O_MIND + (size_t)KMAX*4;
constexpr size_t O_SIDX  = 32768;                      // N ints, then pmin/pidx

__global__ __launch_bounds__(NTHR)
void assign_all(const float* __restrict__ pts,
                const float* __restrict__ gtb,
                const int* __restrict__ glab,
                int* __restrict__ out,     // scratch sxy during pipeline; final output
                char* __restrict__ wsc,
                int N, int K)
{
    cg::grid_group grid = cg::this_grid();
    const int t = threadIdx.x;
    const int b = blockIdx.x;
    const int gsz = gridDim.x * blockDim.x;
    const int tg0 = b * blockDim.x + t;
    const int wv = t >> 6, lane = t & 63;

    int* hist  = (int*)(wsc + O_HIST);
    int* boff  = (int*)(wsc + O_BOFF);
    int* bbase = (int*)(wsc + O_MISC);
    int* bcnt  = bbase + 8;
    float* g_cx  = (float*)(wsc + O_GT);
    float* g_cy  = g_cx + KMAX;
    float* g_w   = g_cx + 2*KMAX;
    float* g_h   = g_cx + 3*KMAX;
    float* g_rw  = g_cx + 4*KMAX;
    float* g_rh  = g_cx + 5*KMAX;
    int*   g_lvl = (int*)(g_cx + 6*KMAX);
    int*   g_org = (int*)(g_cx + 7*KMAX);
    int*   g_inv = (int*)(g_cx + 8*KMAX);
    float* mind  = (float*)(wsc + O_MIND);
    int*   nearg = (int*)(wsc + O_NEARG);
    int*   sidx  = (int*)(wsc + O_SIDX);
    float* pmin  = (float*)(wsc + O_SIDX + (size_t)4*N);
    int*   pidx  = (int*)((char*)pmin + (size_t)NBLK*KMAX*4);
    float2* sxy  = (float2*)out;   // d_out doubles as sorted-xy scratch until phase E

    __shared__ int   sh_hist[8];
    __shared__ int   sh_whist[NWAVE][NLVL];
    __shared__ int   sh_wscan[NWAVE][NLVL];
    __shared__ int   sh_scan[NBLK*NLVL];
    __shared__ float sh_rd[NTHR];
    __shared__ int   sh_ri[NTHR];
    __shared__ int   sh_gl[KMAX];
    __shared__ float sh_fd[KMAX];
    __shared__ int   sh_fn[KMAX];
    __shared__ int   sh_fw[KMAX];
    __shared__ int   sh_mm[2];

    // ---------------- Phase A: per-block level histogram of points ----------------
    if (t < NLVL) sh_hist[t] = 0;
    __syncthreads();
    for (int i = tg0; i < N; i += gsz) {
        unsigned u = __float_as_uint(pts[3*i+2]);
        int e = (int)((u >> 23) & 0xFF) - 127;     // exact log2 (stride is power of 2)
        int bin = min(max(e - 3, 0), NLVL - 1);
        atomicAdd(&sh_hist[bin], 1);
    }
    __syncthreads();
    if (t < NLVL) hist[b*NLVL + t] = sh_hist[t];
    grid.sync();

    // ---------------- Phase B (block 0): prefix sums + gt prep + gt level-sort ----
    if (b == 0) {
        // parallel exclusive scan over the 256 per-block histograms, per bin
        int h[NLVL];
        if (t < NBLK) {
            #pragma unroll
            for (int l = 0; l < NLVL; ++l) { h[l] = hist[t*NLVL + l]; sh_scan[t*NLVL + l] = h[l]; }
        }
        __syncthreads();
        for (int off = 1; off < NBLK; off <<= 1) {
            int a[NLVL] = {0,0,0,0,0};
            if (t < NBLK && t >= off) {
                #pragma unroll
                for (int l = 0; l < NLVL; ++l) a[l] = sh_scan[(t-off)*NLVL + l];
            }
            __syncthreads();
            if (t < NBLK && t >= off) {
                #pragma unroll
                for (int l = 0; l < NLVL; ++l) sh_scan[t*NLVL + l] += a[l];
            }
            __syncthreads();
        }
        if (t < NBLK) {
            #pragma unroll
            for (int l = 0; l < NLVL; ++l) boff[t*NLVL + l] = sh_scan[t*NLVL + l] - h[l];
        }
        if (t == NBLK - 1) {
            #pragma unroll
            for (int l = 0; l < NLVL; ++l) bcnt[l] = sh_scan[t*NLVL + l];
        }
        __syncthreads();
        if (t == 0) {
            int run = 0, mn = 99, mx = -99;
            #pragma unroll
            for (int l = 0; l < NLVL; ++l) {
                bbase[l] = run; run += bcnt[l];
                if (bcnt[l] > 0) { if (l + 3 < mn) mn = l + 3; if (l + 3 > mx) mx = l + 3; }
            }
            sh_mm[0] = mn; sh_mm[1] = mx;
        }
        __syncthreads();
        // gt preprocessing (bit-exact vs reference; passed absmax 0 in round 1)
        float cx = 0.f, cy = 0.f, w = 1.f, h2 = 1.f;
        int bin = 0;
        if (t < K) {
            float x0 = gtb[8*t+0], y0 = gtb[8*t+1], x1 = gtb[8*t+2], y1 = gtb[8*t+3];
            float x2 = gtb[8*t+4], y2 = gtb[8*t+5], x3 = gtb[8*t+6], y3 = gtb[8*t+7];
            float xmin = fminf(fminf(x0, x1), fminf(x2, x3));
            float xmax = fmaxf(fmaxf(x0, x1), fmaxf(x2, x3));
            float ymin = fminf(fminf(y0, y1), fminf(y2, y3));
            float ymax = fmaxf(fmaxf(y0, y1), fmaxf(y2, y3));
            cx = __fmul_rn(__fadd_rn(xmin, xmax), 0.5f);
            cy = __fmul_rn(__fadd_rn(ymin, ymax), 0.5f);
            w  = fmaxf(__fsub_rn(xmax, xmin), 1e-6f);
            h2 = fmaxf(__fsub_rn(ymax, ymin), 1e-6f);
            float gf = __fmul_rn(__fadd_rn(log2f(__fmul_rn(w, 0.25f)),
                                           log2f(__fmul_rn(h2, 0.25f))), 0.5f);
            int gl = (int)gf;
            gl = min(max(gl, sh_mm[0]), sh_mm[1]);
            bin = gl - 3;
            sh_gl[t] = bin;
        }
        __syncthreads();
        if (t < K) {
            // stable slot among (level, orig idx)
            int slot = 0;
            for (int j = 0; j < K; ++j) {
                int bj = sh_gl[j];
                if (bj < bin || (bj == bin && j < t)) slot++;
            }
            g_cx[slot] = cx; g_cy[slot] = cy;
            g_w[slot]  = w;  g_h[slot]  = h2;
            g_rw[slot] = 1.0f / w;       // correctly-rounded reciprocal (IEEE div)
            g_rh[slot] = 1.0f / h2;
            g_lvl[slot] = bin; g_org[slot] = t; g_inv[t] = slot;
        }
    }
    grid.sync();

    // ---------------- Phase C: deterministic stable scatter into level buckets ----
    {
        int iters = (N + gsz - 1) / gsz;
        for (int it = 0; it < iters; ++it) {
            int i = tg0 + it * gsz;
            bool act = i < N;
            int bin = -1; float x = 0.f, y = 0.f;
            if (act) {
                x = pts[3*i]; y = pts[3*i+1];
                unsigned u = __float_as_uint(pts[3*i+2]);
                int e = (int)((u >> 23) & 0xFF) - 127;
                bin = min(max(e - 3, 0), NLVL - 1);
            }
            int rank = 0;
            #pragma unroll
            for (int bb = 0; bb < NLVL; ++bb) {
                unsigned long long m = __ballot(bin == bb);
                if (bin == bb) rank = __popcll(m & ((1ull << lane) - 1ull));
                if (lane == 0) sh_whist[wv][bb] = __popcll(m);
            }
            __syncthreads();
            if (t < NLVL) {
                int run = 0;
                for (int ww = 0; ww < NWAVE; ++ww) { sh_wscan[ww][t] = run; run += sh_whist[ww][t]; }
            }
            __syncthreads();
            if (act) {
                int pos = bbase[bin] + boff[b*NLVL + bin] + sh_wscan[wv][bin] + rank;
                sxy[pos] = make_float2(x, y);
                sidx[pos] = i;
            }
            __syncthreads();
        }
    }
    grid.sync();

    // ---------------- Phase D: per-gt nearest point within its level bucket ------
    {
        const int c = t >> 8;          // 4 segment-copies per gt
        const int g = t & (KMAX - 1);  // sorted gt slot
        float bd = INFIN; int bix = 0x7FFFFFFF;
        if (g < K) {
            float cx = g_cx[g], cy = g_cy[g];
            float ww = g_w[g],  hh = g_h[g];
            float rw = g_rw[g], rh = g_rh[g];
            int bin = g_lvl[g];
            int base = bbase[bin], cnt = bcnt[bin];
            int nseg = NBLK * 4;
            int per = (cnt + nseg - 1) / nseg;
            int i0 = (b * 4 + c) * per;
            int i1 = min(i0 + per, cnt);
            float sthr = INFIN;
            for (int i = i0; i < i1; ++i) {
                float2 xy = sxy[base + i];      // wave-uniform -> broadcast
                int ix = sidx[base + i];
                float dx = __fsub_rn(xy.x, cx);
                float dy = __fsub_rn(xy.y, cy);
                // Markstein: correctly-rounded dx/w via precomputed RN reciprocal
                float qx = __fmul_rn(dx, rw);
                qx = __fmaf_rn(__fmaf_rn(-ww, qx, dx), rw, qx);
                float qy = __fmul_rn(dy, rh);
                qy = __fmaf_rn(__fmaf_rn(-hh, qy, dy), rh, qy);
                float s = __fadd_rn(__fmul_rn(qx, qx), __fmul_rn(qy, qy));
                if (s <= sthr) {                 // conservative candidate filter
                    float d = __fsqrt_rn(s);
                    if (d < bd || (d == bd && ix < bix)) {
                        bd = d; bix = ix;
                        sthr = __fmul_rn(__fmul_rn(bd, bd), 1.000002f);
                    }
                }
            }
        }
        sh_rd[t] = bd; sh_ri[t] = bix;
        __syncthreads();
        if (t < KMAX) {
            float d0 = sh_rd[t]; int j0 = sh_ri[t];
            #pragma unroll
            for (int cc = 1; cc < 4; ++cc) {
                float d1 = sh_rd[cc*KMAX + t]; int j1 = sh_ri[cc*KMAX + t];
                if (d1 < d0 || (d1 == d0 && j1 < j0)) { d0 = d1; j0 = j1; }
            }
            pmin[b*KMAX + t] = d0;
            pidx[b*KMAX + t] = j0;
        }
    }
    grid.sync();

    // ---------------- Phase E: zero output + per-gt reduction over blocks --------
    {
        int2* out2 = (int2*)out;
        for (int i = tg0; i < N; i += gsz) out2[i] = make_int2(0, 0);  // 2N ints
        if (b < K) {
            float d0 = INFIN; int j0 = 0x7FFFFFFF;
            if (t < NBLK) { d0 = pmin[t*KMAX + b]; j0 = pidx[t*KMAX + b]; }
            sh_rd[t] = d0; sh_ri[t] = j0;
            __syncthreads();
            for (int off = NTHR/2; off > 0; off >>= 1) {
                if (t < off) {
                    float d1 = sh_rd[t+off]; int j1 = sh_ri[t+off];
                    if (d1 < sh_rd[t] || (d1 == sh_rd[t] && j1 < sh_ri[t])) { sh_rd[t] = d1; sh_ri[t] = j1; }
                }
                __syncthreads();
            }
            if (t == 0) { mind[b] = sh_rd[0]; nearg[b] = sh_ri[0]; }
        }
    }
    grid.sync();

    // ---------------- Phase F (block 0): contention resolve + scatter ------------
    if (b == 0) {
        int k = t;                      // original gt index
        float dk = INFIN; int nk = 0x7FFFFFFF;
        if (k < K) { int slot = g_inv[k]; dk = mind[slot]; nk = nearg[slot]; }
        if (k < KMAX) { sh_fd[k] = dk; sh_fn[k] = nk; }
        __syncthreads();
        bool win = false;
        if (k < K) {
            bool valid = dk < INFIN;
            float bestv = INFIN;
            for (int j = 0; j < K; ++j)
                if (sh_fn[j] == nk) bestv = fminf(bestv, sh_fd[j]);
            win = valid && (dk == bestv);
        }
        if (k < KMAX) sh_fw[k] = win ? 1 : 0;
        __syncthreads();
        if (win) {
            bool owner = true;
            for (int j = 0; j < k; ++j)
                if (sh_fn[j] == nk && sh_fw[j]) { owner = false; break; }
            if (owner) {
                out[nk]     = k + 1;
                out[N + nk] = glab[k];
            }
        }
    }
}

extern "C" void kernel_launch(void* const* d_in, const int* in_sizes, int n_in,
                              void* d_out, int out_size, void* d_ws, size_t ws_size,
                              hipStream_t stream) {
    const float* pts = (const float*)d_in[0];
    const float* gtb = (const float*)d_in[1];
    const int*  glab = (const int*)d_in[2];
    int N = in_sizes[0] / 3;
    int K = in_sizes[1] / 8;
    int* outp = (int*)d_out;
    char* wsc = (char*)d_ws;
    void* args[] = { (void*)&pts, (void*)&gtb, (void*)&glab,
                     (void*)&outp, (void*)&wsc, (void*)&N, (void*)&K };
    hipLaunchCooperativeKernel((void*)assign_all, dim3(NBLK), dim3(NTHR), args, 0, stream);
}

// Round 3
// 82.004 us; speedup vs baseline: 2.6468x; 2.6468x over previous
//
#include <hip/hip_runtime.h>
#include <cstdint>

#define INFIN __builtin_inff()
constexpr int KMAX = 256;

// ws layout: int2 wsmm[256] @ 0 ; unsigned long long pack[256] @ 4096

// ---------- A: zero output, per-block level min/max, init packs ----------
__global__ __launch_bounds__(256)
void k_pre(const float* __restrict__ pts, int2* __restrict__ wsmm,
           unsigned long long* __restrict__ pack, int4* __restrict__ outz,
           int n4, int N) {
    int t = threadIdx.x, b = blockIdx.x;
    int gid = b * 256 + t, gsz = gridDim.x * 256;
    for (int i = gid; i < n4; i += gsz) outz[i] = make_int4(0, 0, 0, 0);
    int lmin = 127, lmax = -127;
    for (int i = gid; i < N; i += gsz) {
        unsigned u = __float_as_uint(pts[3 * i + 2]);
        int e = (int)((u >> 23) & 0xFF) - 127;   // exact log2 (stride = power of 2)
        lmin = min(lmin, e); lmax = max(lmax, e);
    }
    __shared__ int smin[256], smax[256];
    smin[t] = lmin; smax[t] = lmax;
    __syncthreads();
    for (int off = 128; off > 0; off >>= 1) {
        if (t < off) {
            smin[t] = min(smin[t], smin[t + off]);
            smax[t] = max(smax[t], smax[t + off]);
        }
        __syncthreads();
    }
    if (t == 0) wsmm[b] = make_int2(smin[0], smax[0]);
    if (b == 0 && t < KMAX) pack[t] = ~0ull;
}

// ---------- B: block-local bucketing + distance scan + atomic reduce ----------
__global__ __launch_bounds__(1024)
void k_dist(const float* __restrict__ pts, const float* __restrict__ gtb,
            const int2* __restrict__ wsmm, unsigned long long* __restrict__ pack,
            int N, int K) {
    const int t = threadIdx.x, b = blockIdx.x;
    const int wv = t >> 6, lane = t & 63;

    __shared__ float4 sp[1024];                       // bucketed points (x,y,idx_bits,pad)
    __shared__ float s_cx[KMAX], s_cy[KMAX], s_w[KMAX], s_h[KMAX], s_rw[KMAX], s_rh[KMAX];
    __shared__ int   s_org[KMAX], s_gbin[KMAX];
    __shared__ int   s_wh[16][5], s_wb[16][5], s_pcnt[5], s_gcnt[5];
    __shared__ int   s_mm[2];
    __shared__ int   rmin[256], rmax[256];
    __shared__ float sh_d[1024];
    __shared__ int   sh_ix[1024];

    // phase 0: reduce global level min/max from 256 per-block entries
    if (t < 256) { int2 mm = wsmm[t]; rmin[t] = mm.x; rmax[t] = mm.y; }
    __syncthreads();
    for (int off = 128; off > 0; off >>= 1) {
        if (t < off) {
            rmin[t] = min(rmin[t], rmin[t + off]);
            rmax[t] = max(rmax[t], rmax[t + off]);
        }
        __syncthreads();
    }
    if (t == 0) { s_mm[0] = rmin[0]; s_mm[1] = rmax[0]; }
    __syncthreads();

    // phase 1: gt prep (redundant per block, 1 gt/thread) + level grouping
    float cx = 0.f, cy = 0.f, w = 1.f, h = 1.f, rw = 1.f, rh = 1.f;
    int gbin = 99;
    if (t < K) {
        float x0 = gtb[8*t+0], y0 = gtb[8*t+1], x1 = gtb[8*t+2], y1 = gtb[8*t+3];
        float x2 = gtb[8*t+4], y2 = gtb[8*t+5], x3 = gtb[8*t+6], y3 = gtb[8*t+7];
        float xmin = fminf(fminf(x0, x1), fminf(x2, x3));
        float xmax = fmaxf(fmaxf(x0, x1), fmaxf(x2, x3));
        float ymin = fminf(fminf(y0, y1), fminf(y2, y3));
        float ymax = fmaxf(fmaxf(y0, y1), fmaxf(y2, y3));
        cx = __fmul_rn(__fadd_rn(xmin, xmax), 0.5f);
        cy = __fmul_rn(__fadd_rn(ymin, ymax), 0.5f);
        w  = fmaxf(__fsub_rn(xmax, xmin), 1e-6f);
        h  = fmaxf(__fsub_rn(ymax, ymin), 1e-6f);
        rw = 1.0f / w;                                 // RN reciprocal for Markstein
        rh = 1.0f / h;
        float gf = __fmul_rn(__fadd_rn(log2f(__fmul_rn(w, 0.25f)),
                                       log2f(__fmul_rn(h, 0.25f))), 0.5f);
        int gl = (int)gf;
        gl = min(max(gl, s_mm[0]), s_mm[1]);
        gbin = gl - 3;                                 // data: levels in [3,7]
    }
    int grank = 0;
    if (t < 256) {                                     // waves 0..3 fully active
        #pragma unroll
        for (int bb = 0; bb < 5; ++bb) {
            unsigned long long m = __ballot(gbin == bb);
            if (gbin == bb) grank = __popcll(m & ((1ull << lane) - 1ull));
            if (lane == 0) s_wh[wv][bb] = __popcll(m);
        }
    }
    __syncthreads();
    if (t < 5) {
        int run = 0;
        for (int w2 = 0; w2 < 4; ++w2) { s_wb[w2][t] = run; run += s_wh[w2][t]; }
        s_gcnt[t] = run;
    }
    __syncthreads();
    if (t < K) {
        int base = 0;
        for (int bb = 0; bb < gbin; ++bb) base += s_gcnt[bb];
        int slot = base + s_wb[wv][gbin] + grank;      // permutation of 0..K-1
        s_cx[slot] = cx; s_cy[slot] = cy;
        s_w[slot] = w;   s_h[slot] = h;
        s_rw[slot] = rw; s_rh[slot] = rh;
        s_org[slot] = t; s_gbin[slot] = gbin;
    }
    __syncthreads();

    // phase 2: bucket this block's 1024 points by level into LDS
    int i = b * 1024 + t;
    bool act = (i < N);
    float px = 0.f, py = 0.f;
    int pbin = -1;
    if (act) {
        px = pts[3 * i]; py = pts[3 * i + 1];
        unsigned u = __float_as_uint(pts[3 * i + 2]);
        int e = (int)((u >> 23) & 0xFF) - 127;
        pbin = e - 3;
        if (pbin < 0 || pbin > 4) pbin = -1;
    }
    int prank = 0;
    #pragma unroll
    for (int bb = 0; bb < 5; ++bb) {
        unsigned long long m = __ballot(pbin == bb);
        if (pbin == bb) prank = __popcll(m & ((1ull << lane) - 1ull));
        if (lane == 0) s_wh[wv][bb] = __popcll(m);
    }
    __syncthreads();
    if (t < 5) {
        int run = 0;
        for (int w2 = 0; w2 < 16; ++w2) { s_wb[w2][t] = run; run += s_wh[w2][t]; }
        s_pcnt[t] = run;
    }
    __syncthreads();
    if (pbin >= 0) {
        int base = 0;
        for (int bb = 0; bb < pbin; ++bb) base += s_pcnt[bb];
        int pos = base + s_wb[wv][pbin] + prank;
        sp[pos] = make_float4(px, py, __int_as_float(i), 0.f);
    }
    __syncthreads();

    // phase 3: scan — thread = (gt slot g, copy c); lanes share bucket -> broadcast
    const int c = t >> 8, g = t & 255;
    float bd = INFIN;
    int bix = 0x7FFFFFFF;
    if (g < K) {
        float gcx = s_cx[g], gcy = s_cy[g];
        float gw = s_w[g], gh = s_h[g], grw = s_rw[g], grh = s_rh[g];
        int bin = s_gbin[g];
        int base = 0;
        for (int bb = 0; bb < bin; ++bb) base += s_pcnt[bb];
        int cnt = s_pcnt[bin];
        int seg = (cnt + 3) >> 2;
        int i0 = c * seg, i1 = min(i0 + seg, cnt);
        float sthr = INFIN;
        #pragma unroll 2
        for (int ii = i0; ii < i1; ++ii) {
            float4 q = sp[base + ii];
            float dx = __fsub_rn(q.x, gcx);
            float dy = __fsub_rn(q.y, gcy);
            float qx = __fmul_rn(dx, grw);             // Markstein: == __fdiv_rn(dx, gw)
            qx = __fmaf_rn(__fmaf_rn(-gw, qx, dx), grw, qx);
            float qy = __fmul_rn(dy, grh);
            qy = __fmaf_rn(__fmaf_rn(-gh, qy, dy), grh, qy);
            float s = __fadd_rn(__fmul_rn(qx, qx), __fmul_rn(qy, qy));
            if (s <= sthr) {                           // rare path
                float d = __fsqrt_rn(s);
                int ix = __float_as_int(q.z);
                if (d < bd || (d == bd && ix < bix)) { bd = d; bix = ix; }
                sthr = __fmul_rn(__fmul_rn(bd, bd), 1.000002f);  // >= max s with sqrt(s)<=bd
            }
        }
    }
    sh_d[t] = bd; sh_ix[t] = bix;
    __syncthreads();

    // phase 4: merge 4 copies, one packed atomicMin per gt per block
    if (t < 256) {
        float d0 = sh_d[t]; int x0 = sh_ix[t];
        #pragma unroll
        for (int cc = 1; cc < 4; ++cc) {
            float d1 = sh_d[cc * 256 + t]; int x1 = sh_ix[cc * 256 + t];
            if (d1 < d0 || (d1 == d0 && x1 < x0)) { d0 = d1; x0 = x1; }
        }
        if (t < K && x0 != 0x7FFFFFFF) {
            unsigned long long p =
                ((unsigned long long)__float_as_uint(d0) << 32) | (unsigned)x0;
            atomicMin(&pack[s_org[t]], p);
        }
    }
}

// ---------- C: contention resolve + scatter ----------
__global__ __launch_bounds__(256)
void k_final(const unsigned long long* __restrict__ pack,
             const int* __restrict__ glab, int* __restrict__ out, int N, int K) {
    __shared__ float sd[256];
    __shared__ int sn[256], sw[256];
    int k = threadIdx.x;
    float dk = INFIN; int nk = -1; bool valid = false;
    if (k < K) {
        unsigned long long p = pack[k];
        unsigned db = (unsigned)(p >> 32);
        valid = db < 0x7F800000u;
        if (valid) { dk = __uint_as_float(db); nk = (int)(unsigned)(p & 0xFFFFFFFFu); }
    }
    sd[k] = dk; sn[k] = nk;
    __syncthreads();
    float bestv = INFIN;
    for (int j = 0; j < K; ++j)
        if (sn[j] == nk) bestv = fminf(bestv, sd[j]);
    bool win = valid && (dk == bestv);
    sw[k] = win ? 1 : 0;
    __syncthreads();
    if (win) {
        bool owner = true;
        for (int j = 0; j < k; ++j)
            if (sn[j] == nk && sw[j]) { owner = false; break; }
        if (owner) {
            out[nk]     = k + 1;
            out[N + nk] = glab[k];
        }
    }
}

extern "C" void kernel_launch(void* const* d_in, const int* in_sizes, int n_in,
                              void* d_out, int out_size, void* d_ws, size_t ws_size,
                              hipStream_t stream) {
    const float* pts = (const float*)d_in[0];
    const float* gtb = (const float*)d_in[1];
    const int*  glab = (const int*)d_in[2];
    int N = in_sizes[0] / 3;
    int K = in_sizes[1] / 8;
    int2* wsmm = (int2*)d_ws;
    unsigned long long* pack = (unsigned long long*)((char*)d_ws + 4096);

    k_pre<<<256, 256, 0, stream>>>(pts, wsmm, pack, (int4*)d_out, out_size / 4, N);
    k_dist<<<(N + 1023) / 1024, 1024, 0, stream>>>(pts, gtb, (const int2*)wsmm, pack, N, K);
    k_final<<<1, 256, 0, stream>>>(pack, glab, (int*)d_out, N, K);
}

// Round 4
// 40.303 us; speedup vs baseline: 5.3855x; 2.0347x over previous
//
#include <hip/hip_runtime.h>
#include <cstdint>

#define INFIN __builtin_inff()
constexpr int KMAX = 256;

// ws layout: int2 wsmm[256] @ 0 ; unsigned long long pack[256] @ 4096

// ---------- A: zero output, per-block level min/max, init packs ----------
__global__ __launch_bounds__(256)
void k_pre(const float* __restrict__ pts, int2* __restrict__ wsmm,
           unsigned long long* __restrict__ pack, int4* __restrict__ outz,
           int n4, int N) {
    int t = threadIdx.x, b = blockIdx.x;
    int gid = b * 256 + t, gsz = gridDim.x * 256;
    for (int i = gid; i < n4; i += gsz) outz[i] = make_int4(0, 0, 0, 0);
    int lmin = 127, lmax = -127;
    for (int i = gid; i < N; i += gsz) {
        unsigned u = __float_as_uint(pts[3 * i + 2]);
        int e = (int)((u >> 23) & 0xFF) - 127;   // exact log2 (stride = power of 2)
        lmin = min(lmin, e); lmax = max(lmax, e);
    }
    __shared__ int smin[256], smax[256];
    smin[t] = lmin; smax[t] = lmax;
    __syncthreads();
    for (int off = 128; off > 0; off >>= 1) {
        if (t < off) {
            smin[t] = min(smin[t], smin[t + off]);
            smax[t] = max(smax[t], smax[t + off]);
        }
        __syncthreads();
    }
    if (t == 0) wsmm[b] = make_int2(smin[0], smax[0]);
    if (b == 0 && t < KMAX) pack[t] = ~0ull;
}

// ---------- B: block-local bucketing + distance scan + atomic reduce ----------
__global__ __launch_bounds__(1024)
void k_dist(const float* __restrict__ pts, const float* __restrict__ gtb,
            const int2* __restrict__ wsmm, unsigned long long* __restrict__ pack,
            int N, int K) {
    const int t = threadIdx.x, b = blockIdx.x;
    const int wv = t >> 6, lane = t & 63;

    __shared__ float4 sp[1024];                       // bucketed points (x,y,idx_bits,pad)
    __shared__ float s_cx[KMAX], s_cy[KMAX], s_w[KMAX], s_h[KMAX], s_rw[KMAX], s_rh[KMAX];
    __shared__ int   s_org[KMAX], s_gbin[KMAX];
    __shared__ int   s_wh[16][5], s_wb[16][5], s_pcnt[5], s_gcnt[5];
    __shared__ int   s_mm[2];
    __shared__ int   rmin[256], rmax[256];
    __shared__ float sh_d[1024];
    __shared__ int   sh_ix[1024];

    // phase 0: reduce global level min/max from 256 per-block entries
    if (t < 256) { int2 mm = wsmm[t]; rmin[t] = mm.x; rmax[t] = mm.y; }
    __syncthreads();
    for (int off = 128; off > 0; off >>= 1) {
        if (t < off) {
            rmin[t] = min(rmin[t], rmin[t + off]);
            rmax[t] = max(rmax[t], rmax[t + off]);
        }
        __syncthreads();
    }
    if (t == 0) { s_mm[0] = rmin[0]; s_mm[1] = rmax[0]; }
    __syncthreads();

    // phase 1: gt prep (redundant per block, 1 gt/thread) + level grouping
    float cx = 0.f, cy = 0.f, w = 1.f, h = 1.f, rw = 1.f, rh = 1.f;
    int gbin = 99;
    if (t < K) {
        float x0 = gtb[8*t+0], y0 = gtb[8*t+1], x1 = gtb[8*t+2], y1 = gtb[8*t+3];
        float x2 = gtb[8*t+4], y2 = gtb[8*t+5], x3 = gtb[8*t+6], y3 = gtb[8*t+7];
        float xmin = fminf(fminf(x0, x1), fminf(x2, x3));
        float xmax = fmaxf(fmaxf(x0, x1), fmaxf(x2, x3));
        float ymin = fminf(fminf(y0, y1), fminf(y2, y3));
        float ymax = fmaxf(fmaxf(y0, y1), fmaxf(y2, y3));
        cx = __fmul_rn(__fadd_rn(xmin, xmax), 0.5f);
        cy = __fmul_rn(__fadd_rn(ymin, ymax), 0.5f);
        w  = fmaxf(__fsub_rn(xmax, xmin), 1e-6f);
        h  = fmaxf(__fsub_rn(ymax, ymin), 1e-6f);
        rw = 1.0f / w;                                 // RN reciprocal for Markstein
        rh = 1.0f / h;
        float gf = __fmul_rn(__fadd_rn(log2f(__fmul_rn(w, 0.25f)),
                                       log2f(__fmul_rn(h, 0.25f))), 0.5f);
        int gl = (int)gf;
        gl = min(max(gl, s_mm[0]), s_mm[1]);
        gbin = min(max(gl - 3, 0), 4);                 // data: levels in [3,7]
    }
    int grank = 0;
    if (t < 256) {                                     // waves 0..3 fully active
        #pragma unroll
        for (int bb = 0; bb < 5; ++bb) {
            unsigned long long m = __ballot(gbin == bb);
            if (gbin == bb) grank = __popcll(m & ((1ull << lane) - 1ull));
            if (lane == 0) s_wh[wv][bb] = __popcll(m);
        }
    }
    __syncthreads();
    if (t < 5) {
        int run = 0;
        for (int w2 = 0; w2 < 4; ++w2) { s_wb[w2][t] = run; run += s_wh[w2][t]; }
        s_gcnt[t] = run;
    }
    __syncthreads();
    if (t < K) {
        int base = 0;
        for (int bb = 0; bb < gbin; ++bb) base += s_gcnt[bb];
        int slot = base + s_wb[wv][gbin] + grank;      // permutation of 0..K-1
        s_cx[slot] = cx; s_cy[slot] = cy;
        s_w[slot] = w;   s_h[slot] = h;
        s_rw[slot] = rw; s_rh[slot] = rh;
        s_org[slot] = t; s_gbin[slot] = gbin;
    }
    __syncthreads();

    // phase 2: bucket this block's 1024 points by level into LDS
    int i = b * 1024 + t;
    bool act = (i < N);
    float px = 0.f, py = 0.f;
    int pbin = -1;
    if (act) {
        px = pts[3 * i]; py = pts[3 * i + 1];
        unsigned u = __float_as_uint(pts[3 * i + 2]);
        int e = (int)((u >> 23) & 0xFF) - 127;
        pbin = e - 3;
        if (pbin < 0 || pbin > 4) pbin = -1;
    }
    int prank = 0;
    #pragma unroll
    for (int bb = 0; bb < 5; ++bb) {
        unsigned long long m = __ballot(pbin == bb);
        if (pbin == bb) prank = __popcll(m & ((1ull << lane) - 1ull));
        if (lane == 0) s_wh[wv][bb] = __popcll(m);
    }
    __syncthreads();
    if (t < 5) {
        int run = 0;
        for (int w2 = 0; w2 < 16; ++w2) { s_wb[w2][t] = run; run += s_wh[w2][t]; }
        s_pcnt[t] = run;
    }
    __syncthreads();
    if (pbin >= 0) {
        int base = 0;
        for (int bb = 0; bb < pbin; ++bb) base += s_pcnt[bb];
        int pos = base + s_wb[wv][pbin] + prank;
        sp[pos] = make_float4(px, py, __int_as_float(i), 0.f);
    }
    __syncthreads();

    // phase 3: scan — thread = (gt slot g, copy c); lanes share bucket -> broadcast
    const int c = t >> 8, g = t & 255;
    float bd = INFIN;
    int bix = 0x7FFFFFFF;
    if (g < K) {
        float gcx = s_cx[g], gcy = s_cy[g];
        float gw = s_w[g], gh = s_h[g], grw = s_rw[g], grh = s_rh[g];
        int bin = s_gbin[g];
        int base = 0;
        for (int bb = 0; bb < bin; ++bb) base += s_pcnt[bb];
        int cnt = s_pcnt[bin];
        int seg = (cnt + 3) >> 2;
        int i0 = c * seg, i1 = min(i0 + seg, cnt);
        float sthr = INFIN;
        #pragma unroll 2
        for (int ii = i0; ii < i1; ++ii) {
            float4 q = sp[base + ii];
            float dx = __fsub_rn(q.x, gcx);
            float dy = __fsub_rn(q.y, gcy);
            float qx = __fmul_rn(dx, grw);             // Markstein: == __fdiv_rn(dx, gw)
            qx = __fmaf_rn(__fmaf_rn(-gw, qx, dx), grw, qx);
            float qy = __fmul_rn(dy, grh);
            qy = __fmaf_rn(__fmaf_rn(-gh, qy, dy), grh, qy);
            float s = __fadd_rn(__fmul_rn(qx, qx), __fmul_rn(qy, qy));
            if (s <= sthr) {                           // rare path
                float d = __fsqrt_rn(s);
                int ix = __float_as_int(q.z);
                if (d < bd || (d == bd && ix < bix)) { bd = d; bix = ix; }
                sthr = __fmul_rn(__fmul_rn(bd, bd), 1.000002f);  // >= max s with sqrt(s)<=bd
            }
        }
    }
    sh_d[t] = bd; sh_ix[t] = bix;
    __syncthreads();

    // phase 4: merge 4 copies, one packed atomicMin per gt per block
    if (t < 256) {
        float d0 = sh_d[t]; int x0 = sh_ix[t];
        #pragma unroll
        for (int cc = 1; cc < 4; ++cc) {
            float d1 = sh_d[cc * 256 + t]; int x1 = sh_ix[cc * 256 + t];
            if (d1 < d0 || (d1 == d0 && x1 < x0)) { d0 = d1; x0 = x1; }
        }
        if (t < K && x0 != 0x7FFFFFFF) {
            unsigned long long p =
                ((unsigned long long)__float_as_uint(d0) << 32) | (unsigned)x0;
            atomicMin(&pack[s_org[t]], p);
        }
    }
}

// ---------- C: contention resolve via LDS hash + scatter ----------
__global__ __launch_bounds__(256)
void k_final(const unsigned long long* __restrict__ pack,
             const int* __restrict__ glab, int* __restrict__ out, int N, int K) {
    __shared__ int hkey[512];
    __shared__ unsigned long long hval[512];
    int k = threadIdx.x;
    hkey[k] = -1; hkey[k + 256] = -1;
    hval[k] = ~0ull; hval[k + 256] = ~0ull;
    __syncthreads();

    int nk = -1;
    unsigned db = 0;
    bool valid = false;
    if (k < K) {
        unsigned long long p = pack[k];
        db = (unsigned)(p >> 32);
        valid = db < 0x7F800000u;                 // finite distance found
        nk = (int)(unsigned)(p & 0xFFFFFFFFu);
    }

    int h = 0;
    if (valid) {
        // insert (nk -> min (dist, gt_idx)) into open-addressing hash
        unsigned long long myp = ((unsigned long long)db << 32) | (unsigned)k;
        h = (int)((((unsigned)nk) * 2654435761u) >> 23) & 511;
        while (true) {
            int old = atomicCAS(&hkey[h], -1, nk);
            if (old == -1 || old == nk) { atomicMin(&hval[h], myp); break; }
            h = (h + 1) & 511;
        }
    }
    __syncthreads();
    if (valid) {
        // h still points at our key's slot; lex-min pack's low word = owner gt
        if ((int)(unsigned)(hval[h] & 0xFFFFFFFFu) == k) {
            out[nk]     = k + 1;
            out[N + nk] = glab[k];
        }
    }
}

extern "C" void kernel_launch(void* const* d_in, const int* in_sizes, int n_in,
                              void* d_out, int out_size, void* d_ws, size_t ws_size,
                              hipStream_t stream) {
    const float* pts = (const float*)d_in[0];
    const float* gtb = (const float*)d_in[1];
    const int*  glab = (const int*)d_in[2];
    int N = in_sizes[0] / 3;
    int K = in_sizes[1] / 8;
    int2* wsmm = (int2*)d_ws;
    unsigned long long* pack = (unsigned long long*)((char*)d_ws + 4096);

    k_pre<<<256, 256, 0, stream>>>(pts, wsmm, pack, (int4*)d_out, out_size / 4, N);
    k_dist<<<(N + 1023) / 1024, 1024, 0, stream>>>(pts, gtb, (const int2*)wsmm, pack, N, K);
    k_final<<<1, 256, 0, stream>>>(pack, glab, (int*)d_out, N, K);
}

// Round 5
// 33.481 us; speedup vs baseline: 6.4828x; 1.2038x over previous
//
#include <hip/hip_runtime.h>
#include <cstdint>

#define INFIN __builtin_inff()
constexpr int KMAX = 256;
constexpr int NB   = 256;   // fixed grid for k_dist

// ws layout: int2 wsmm[256] @ 0 ; u64 pack2[NB*256] @ 4096 (512 KB)

// ---------- A: zero output + per-block level min/max ----------
__global__ __launch_bounds__(256)
void k_pre(const float* __restrict__ pts, int2* __restrict__ wsmm,
           int4* __restrict__ outz, int n4, int N) {
    int t = threadIdx.x, b = blockIdx.x;
    int gid = b * 256 + t, gsz = gridDim.x * 256;
    for (int i = gid; i < n4; i += gsz) outz[i] = make_int4(0, 0, 0, 0);
    int lmin = 127, lmax = -127;
    for (int i = gid; i < N; i += gsz) {
        unsigned u = __float_as_uint(pts[3 * i + 2]);
        int e = (int)((u >> 23) & 0xFF) - 127;   // exact log2 (stride = power of 2)
        lmin = min(lmin, e); lmax = max(lmax, e);
    }
    __shared__ int smin[256], smax[256];
    smin[t] = lmin; smax[t] = lmax;
    __syncthreads();
    for (int off = 128; off > 0; off >>= 1) {
        if (t < off) {
            smin[t] = min(smin[t], smin[t + off]);
            smax[t] = max(smax[t], smax[t + off]);
        }
        __syncthreads();
    }
    if (t == 0) wsmm[b] = make_int2(smin[0], smax[0]);
}

// ---------- B: block-local bucketing + branchless scan + private-row store ----------
__global__ __launch_bounds__(1024)
void k_dist(const float* __restrict__ pts, const float* __restrict__ gtb,
            const int2* __restrict__ wsmm, unsigned long long* __restrict__ pack2,
            int N, int K) {
    const int t = threadIdx.x, b = blockIdx.x;
    const int wv = t >> 6, lane = t & 63;

    __shared__ float4 sp[1024];                     // bucketed points (x,y,idx_bits,pad)
    __shared__ float s_cx[KMAX], s_cy[KMAX], s_w[KMAX], s_h[KMAX], s_rw[KMAX], s_rh[KMAX];
    __shared__ int   s_org[KMAX], s_gbin[KMAX];
    __shared__ int   s_wh[16][5], s_wb[16][5], s_pcnt[5], s_gcnt[5];
    __shared__ int   s_mm[2];
    __shared__ unsigned long long sh_p[1024];

    // phase 0: single-wave reduce of global level min/max
    if (t < 64) {
        int2 a = wsmm[t], b2 = wsmm[t + 64], c2 = wsmm[t + 128], d2 = wsmm[t + 192];
        int lmin = min(min(a.x, b2.x), min(c2.x, d2.x));
        int lmax = max(max(a.y, b2.y), max(c2.y, d2.y));
        #pragma unroll
        for (int off = 32; off > 0; off >>= 1) {
            lmin = min(lmin, __shfl_xor(lmin, off));
            lmax = max(lmax, __shfl_xor(lmax, off));
        }
        if (t == 0) { s_mm[0] = lmin; s_mm[1] = lmax; }
    }

    // phase 1a: gt prep (independent of s_mm)
    float cx = 0.f, cy = 0.f, w = 1.f, h = 1.f, rw = 1.f, rh = 1.f, gf = 0.f;
    if (t < K) {
        float x0 = gtb[8*t+0], y0 = gtb[8*t+1], x1 = gtb[8*t+2], y1 = gtb[8*t+3];
        float x2 = gtb[8*t+4], y2 = gtb[8*t+5], x3 = gtb[8*t+6], y3 = gtb[8*t+7];
        float xmin = fminf(fminf(x0, x1), fminf(x2, x3));
        float xmax = fmaxf(fmaxf(x0, x1), fmaxf(x2, x3));
        float ymin = fminf(fminf(y0, y1), fminf(y2, y3));
        float ymax = fmaxf(fmaxf(y0, y1), fmaxf(y2, y3));
        cx = __fmul_rn(__fadd_rn(xmin, xmax), 0.5f);
        cy = __fmul_rn(__fadd_rn(ymin, ymax), 0.5f);
        w  = fmaxf(__fsub_rn(xmax, xmin), 1e-6f);
        h  = fmaxf(__fsub_rn(ymax, ymin), 1e-6f);
        rw = 1.0f / w;                               // RN reciprocal for Markstein
        rh = 1.0f / h;
        gf = __fmul_rn(__fadd_rn(log2f(__fmul_rn(w, 0.25f)),
                                 log2f(__fmul_rn(h, 0.25f))), 0.5f);
    }
    __syncthreads();

    // phase 1b: level clamp + stable level-grouping of gts (identical in every block)
    int gbin = 99;
    if (t < K) {
        int gl = (int)gf;
        gl = min(max(gl, s_mm[0]), s_mm[1]);
        gbin = min(max(gl - 3, 0), 4);               // data levels in [3,7]
    }
    int grank = 0;
    if (t < 256) {                                   // waves 0..3 fully active
        #pragma unroll
        for (int bb = 0; bb < 5; ++bb) {
            unsigned long long m = __ballot(gbin == bb);
            if (gbin == bb) grank = __popcll(m & ((1ull << lane) - 1ull));
            if (lane == 0) s_wh[wv][bb] = __popcll(m);
        }
    }
    __syncthreads();
    if (t < 5) {
        int run = 0;
        for (int w2 = 0; w2 < 4; ++w2) { s_wb[w2][t] = run; run += s_wh[w2][t]; }
        s_gcnt[t] = run;
    }
    __syncthreads();
    if (t < K) {
        int base = 0;
        for (int bb = 0; bb < gbin; ++bb) base += s_gcnt[bb];
        int slot = base + s_wb[wv][gbin] + grank;    // permutation of 0..K-1
        s_cx[slot] = cx; s_cy[slot] = cy;
        s_w[slot] = w;   s_h[slot] = h;
        s_rw[slot] = rw; s_rh[slot] = rh;
        s_org[slot] = t; s_gbin[slot] = gbin;
    }
    __syncthreads();

    // per-thread running best for its (gt slot, copy)
    const int c = t >> 8, g = t & 255;
    float gcx = 0.f, gcy = 0.f, gw = 1.f, gh = 1.f, grw = 1.f, grh = 1.f;
    int gbin2 = 0;
    if (g < K) {
        gcx = s_cx[g]; gcy = s_cy[g];
        gw = s_w[g];  gh = s_h[g];
        grw = s_rw[g]; grh = s_rh[g];
        gbin2 = s_gbin[g];
    }
    unsigned long long bp = ~0ull;

    // tile loop: each block handles tiles b, b+NB, ...
    for (int tile = b; tile * 1024 < N; tile += NB) {
        __syncthreads();                             // protect sp/s_pcnt reuse

        // phase 2: bucket this tile's 1024 points by level into LDS
        int i = tile * 1024 + t;
        float px = 0.f, py = 0.f;
        int pbin = -1;
        if (i < N) {
            px = pts[3 * i]; py = pts[3 * i + 1];
            unsigned u = __float_as_uint(pts[3 * i + 2]);
            int e = (int)((u >> 23) & 0xFF) - 127;
            pbin = e - 3;
            if (pbin < 0 || pbin > 4) pbin = -1;
        }
        int prank = 0;
        #pragma unroll
        for (int bb = 0; bb < 5; ++bb) {
            unsigned long long m = __ballot(pbin == bb);
            if (pbin == bb) prank = __popcll(m & ((1ull << lane) - 1ull));
            if (lane == 0) s_wh[wv][bb] = __popcll(m);
        }
        __syncthreads();
        if (t < 5) {
            int run = 0;
            for (int w2 = 0; w2 < 16; ++w2) { s_wb[w2][t] = run; run += s_wh[w2][t]; }
            s_pcnt[t] = run;
        }
        __syncthreads();
        if (pbin >= 0) {
            int base = 0;
            for (int bb = 0; bb < pbin; ++bb) base += s_pcnt[bb];
            int pos = base + s_wb[wv][pbin] + prank;
            sp[pos] = make_float4(px, py, __int_as_float(i), 0.f);
        }
        __syncthreads();

        // phase 3: branchless scan of this gt's level bucket (broadcast LDS reads)
        if (g < K) {
            int base = 0;
            for (int bb = 0; bb < gbin2; ++bb) base += s_pcnt[bb];
            int cnt = s_pcnt[gbin2];
            int seg = (cnt + 3) >> 2;
            int i0 = c * seg, i1 = min(i0 + seg, cnt);
            #pragma unroll 4
            for (int ii = i0; ii < i1; ++ii) {
                float4 q = sp[base + ii];
                float dx = __fsub_rn(q.x, gcx);
                float dy = __fsub_rn(q.y, gcy);
                float qx = __fmul_rn(dx, grw);       // Markstein: == __fdiv_rn(dx, gw)
                qx = __fmaf_rn(__fmaf_rn(-gw, qx, dx), grw, qx);
                float qy = __fmul_rn(dy, grh);
                qy = __fmaf_rn(__fmaf_rn(-gh, qy, dy), grh, qy);
                float s = __fadd_rn(__fmul_rn(qx, qx), __fmul_rn(qy, qy));
                float d = __fsqrt_rn(s);
                unsigned long long cand =
                    ((unsigned long long)__float_as_uint(d) << 32)
                    | (unsigned)__float_as_int(q.z);
                bp = cand < bp ? cand : bp;          // lex-min (d, idx)
            }
        }
    }

    // phase 4: merge 4 copies, plain store to this block's private row (by ORIGINAL gt)
    sh_p[t] = bp;
    __syncthreads();
    if (t < K) {
        unsigned long long p0 = sh_p[t];
        #pragma unroll
        for (int cc = 1; cc < 4; ++cc) {
            unsigned long long p1 = sh_p[cc * 256 + t];
            p0 = p1 < p0 ? p1 : p0;
        }
        pack2[(size_t)b * 256 + s_org[t]] = p0;
    }
}

// ---------- C: grid reduce + contention resolve via LDS hash + scatter ----------
__global__ __launch_bounds__(1024)
void k_final(const unsigned long long* __restrict__ pack2,
             const int* __restrict__ glab, int* __restrict__ out, int N, int K) {
    __shared__ unsigned long long sh_p[1024];
    __shared__ int hkey[512];
    __shared__ unsigned long long hval[512];
    const int t = threadIdx.x;
    const int c = t >> 8, k = t & 255;

    if (t < 512) { hkey[t] = -1; hval[t] = ~0ull; }

    // reduce over the 256 block rows (coalesced 512B per wave per iter)
    unsigned long long best = ~0ull;
    #pragma unroll 8
    for (int b = c; b < NB; b += 4) {
        unsigned long long v = pack2[(size_t)b * 256 + k];
        best = v < best ? v : best;
    }
    sh_p[t] = best;
    __syncthreads();

    if (t < 256) {
        unsigned long long p = sh_p[t];
        #pragma unroll
        for (int cc = 1; cc < 4; ++cc) {
            unsigned long long p1 = sh_p[cc * 256 + t];
            p = p1 < p ? p1 : p;
        }
        unsigned db = (unsigned)(p >> 32);
        bool valid = (t < K) && (db < 0x7F800000u);
        int nk = (int)(unsigned)(p & 0xFFFFFFFFu);

        int h = 0;
        if (valid) {
            unsigned long long myp = ((unsigned long long)db << 32) | (unsigned)t;
            h = (int)((((unsigned)nk) * 2654435761u) >> 23) & 511;
            while (true) {
                int old = atomicCAS(&hkey[h], -1, nk);
                if (old == -1 || old == nk) { atomicMin(&hval[h], myp); break; }
                h = (h + 1) & 511;
            }
        }
        __syncthreads();
        if (valid && (int)(unsigned)(hval[h] & 0xFFFFFFFFu) == t) {
            out[nk]     = t + 1;
            out[N + nk] = glab[t];
        }
    } else {
        __syncthreads();
    }
}

extern "C" void kernel_launch(void* const* d_in, const int* in_sizes, int n_in,
                              void* d_out, int out_size, void* d_ws, size_t ws_size,
                              hipStream_t stream) {
    const float* pts = (const float*)d_in[0];
    const float* gtb = (const float*)d_in[1];
    const int*  glab = (const int*)d_in[2];
    int N = in_sizes[0] / 3;
    int K = in_sizes[1] / 8;
    int2* wsmm = (int2*)d_ws;
    unsigned long long* pack2 = (unsigned long long*)((char*)d_ws + 4096);

    k_pre<<<256, 256, 0, stream>>>(pts, wsmm, (int4*)d_out, out_size / 4, N);
    k_dist<<<NB, 1024, 0, stream>>>(pts, gtb, (const int2*)wsmm, pack2, N, K);
    k_final<<<1, 1024, 0, stream>>>(pack2, glab, (int*)d_out, N, K);
}